// Round 5
// baseline (20118.060 us; speedup 1.0000x reference)
//
#include <hip/hip_runtime.h>
#include <hip/hip_cooperative_groups.h>
#include <math.h>

namespace cg = cooperative_groups;

#define BZ 4096
#define NT 128
#define DH 128
#define DI 32
#define LDW 132      // padded row stride (floats) for 128-wide fp32 LDS tiles
#define SCR_KS 2116  // scratch per-ks-plane stride (16*132 + 4)
#define SA 136       // bf16 act tile row stride
#define ST 40        // transposed tile stride (shorts)
#define HF 132       // fp32 h tile stride

typedef short bf16x8 __attribute__((ext_vector_type(8)));
typedef float f32x4 __attribute__((ext_vector_type(4)));

__device__ __forceinline__ float4 ld4(const float* p) { return *(const float4*)(p); }
__device__ __forceinline__ void st4(float* p, float4 v) { *(float4*)(p) = v; }
__device__ __forceinline__ float dot4(float4 w, float4 a) {
  return w.x*a.x + w.y*a.y + w.z*a.z + w.w*a.w;
}
__device__ __forceinline__ float sigm(float x) { return 1.f / (1.f + expf(-x)); }
__device__ __forceinline__ unsigned short f2b(float x) {
  unsigned u = __float_as_uint(x);
  u += 0x7FFFu + ((u >> 16) & 1u);
  return (unsigned short)(u >> 16);
}
__device__ __forceinline__ float b2f(unsigned short b) {
  unsigned u = ((unsigned)b) << 16;
  return __uint_as_float(u);
}

// ---------------- weight prep: fp32 -> bf16 tiles [a2a|a2b|wihR|whhR|wihZ|whhZ|wihN|whhN|outw]
__global__ __launch_bounds__(512) void k_prep(const float* __restrict__ a2w,
                                              const float* __restrict__ wih,
                                              const float* __restrict__ whh,
                                              const float* __restrict__ outw,
                                              unsigned short* __restrict__ wbf) {
  const int idx = blockIdx.x * 512 + threadIdx.x;
  if (idx >= 135168) return;
  const int tile = idx >> 14, pos = idx & 16383;
  float v;
  if (tile == 0)      v = a2w[(pos >> 7) * 256 + (pos & 127)];
  else if (tile == 1) v = a2w[(pos >> 7) * 256 + 128 + (pos & 127)];
  else if (tile == 2) v = wih[pos];
  else if (tile == 3) v = whh[pos];
  else if (tile == 4) v = wih[16384 + pos];
  else if (tile == 5) v = whh[16384 + pos];
  else if (tile == 6) v = wih[32768 + pos];
  else if (tile == 7) v = whh[32768 + pos];
  else                v = outw[pos];
  wbf[idx] = f2b(v);
}

// ---------------- bootstrap scores partials: 64 blocks x 64 rows
template<int D>
__global__ __launch_bounds__(512) void k_scores(const float* __restrict__ hsrc,
                                                const float* __restrict__ enc,
                                                int t, float* __restrict__ spart) {
  constexpr int IG = D / 8;
  constexpr int JC = (D == 128) ? 4 : 1;
  constexpr int HS = D + 4;
  __shared__ float hs[64 * HS];
  __shared__ float es[64 * LDW];
  const int p = blockIdx.x, tid = threadIdx.x, b0 = p * 64;
  for (int idx = tid; idx < 64 * (D / 4); idx += 512) {
    const int r = idx / (D / 4), c4 = (idx % (D / 4)) * 4;
    st4(hs + r * HS + c4, ld4(hsrc + (size_t)(b0 + r) * D + c4));
  }
  for (int idx = tid; idx < 64 * 32; idx += 512) {
    const int r = idx >> 5, c4 = (idx & 31) << 2;
    st4(es + r * LDW + c4, ld4(enc + ((size_t)(b0 + r) * NT + t) * DH + c4));
  }
  __syncthreads();
  const int ig = tid % IG, jg = tid / IG;
  const int i0 = ig * 8, j0 = jg * JC;
  float acc[8][JC];
#pragma unroll
  for (int a = 0; a < 8; ++a)
#pragma unroll
    for (int b = 0; b < JC; ++b) acc[a][b] = 0.f;
  for (int b = 0; b < 64; ++b) {
    float4 h0 = ld4(hs + b * HS + i0);
    float4 h1 = ld4(hs + b * HS + i0 + 4);
    float hv[8] = {h0.x, h0.y, h0.z, h0.w, h1.x, h1.y, h1.z, h1.w};
    float ev[JC];
    if (JC == 4) {
      float4 e = ld4(es + b * LDW + j0);
      ev[0] = e.x; ev[1] = e.y; ev[2] = e.z; ev[3] = e.w;
    } else {
      ev[0] = es[b * LDW + j0];
    }
#pragma unroll
    for (int ii = 0; ii < 8; ++ii)
#pragma unroll
      for (int jj = 0; jj < JC; ++jj) acc[ii][jj] += hv[ii] * ev[jj];
  }
#pragma unroll
  for (int ii = 0; ii < 8; ++ii)
#pragma unroll
    for (int jj = 0; jj < JC; ++jj)
      spart[((size_t)p * D + (i0 + ii)) * 128 + j0 + jj] = acc[ii][jj];
}

// ---------------- bootstrap: reduce P partials + row softmax -> fp32 W and bf16 W
template<int R, int P>
__global__ __launch_bounds__(128) void k_soft(const float* __restrict__ spart,
                                              float* __restrict__ W,
                                              unsigned short* __restrict__ Wmb) {
  const int r = blockIdx.x, j = threadIdx.x;
  float s = 0.f;
#pragma unroll 8
  for (int p = 0; p < P; ++p) s += spart[((size_t)p * R + r) * 128 + j];
  __shared__ float xm[2], xs[2];
  float m = s;
  for (int o = 1; o < 64; o <<= 1) m = fmaxf(m, __shfl_xor(m, o));
  if ((j & 63) == 0) xm[j >> 6] = m;
  __syncthreads();
  m = fmaxf(xm[0], xm[1]);
  float e = expf(s - m);
  float sum = e;
  for (int o = 1; o < 64; o <<= 1) sum += __shfl_xor(sum, o);
  if ((j & 63) == 0) xs[j >> 6] = sum;
  __syncthreads();
  sum = xs[0] + xs[1];
  const float val = e / sum;
  W[r * 128 + j] = val;
  Wmb[r * 128 + j] = f2b(val);
}

// ---------------- MFMA helpers
struct TileRegs { uint4 v[4]; };

__device__ __forceinline__ void loadT(TileRegs& tr, const unsigned short* __restrict__ s,
                                      int tid, int full) {
  const int r0 = tid >> 4, c8 = (tid & 15) * 8;
#pragma unroll
  for (int p = 0; p < 4; ++p)
    if (p == 0 || full) tr.v[p] = *(const uint4*)(s + (size_t)(r0 + 32 * p) * 128 + c8);
}
__device__ __forceinline__ void writeT(const TileRegs& tr, unsigned short* dst,
                                       int tid, int full) {
  const int r0 = tid >> 4, c = tid & 15;
#pragma unroll
  for (int p = 0; p < 4; ++p)
    if (p == 0 || full) {
      const int R = r0 + 32 * p;
      *(uint4*)((char*)dst + ((R * 256 + c * 16) ^ ((R & 7) << 4))) = tr.v[p];
    }
}
// acc[r<16][c] += sum_k act[r][k] * W[c][k]; W tile swizzled, act stride SA
__device__ __forceinline__ void mm16(f32x4& acc, const unsigned short* Wt,
                                     const unsigned short* act, int w, int l) {
  const int n = l & 15, g = l >> 4;
  const int R = w * 16 + n;
  const char* ab = (const char*)act + n * (2 * SA) + g * 16;
  const char* wb = (const char*)Wt;
  const int sw = (R & 7) << 4;
#pragma unroll
  for (int ks = 0; ks < 4; ++ks) {
    bf16x8 b = *(const bf16x8*)(wb + ((R * 256 + ks * 64 + g * 16) ^ sw));
    bf16x8 a = *(const bf16x8*)(ab + ks * 64);
    acc = __builtin_amdgcn_mfma_f32_16x16x32_bf16(a, b, acc, 0, 0, 0);
  }
}

// ---------------- persistent cooperative kernel: steps 1..127
__global__ __launch_bounds__(512, 2) void k_persist(
    const float* __restrict__ enc,
    unsigned short* __restrict__ Wmb,
    const unsigned short* __restrict__ wbf,
    const float* __restrict__ att2b,
    const float* __restrict__ bih, const float* __restrict__ bhh,
    const float* __restrict__ outb,
    const float* __restrict__ hinit,
    float* __restrict__ out,
    unsigned short* __restrict__ spart) {
  cg::grid_group grid = cg::this_grid();
  __shared__ __align__(16) unsigned short Wslot[2][16384];
  __shared__ __align__(16) unsigned short el[16 * SA], hl[16 * SA];
  __shared__ __align__(16) unsigned short ctxl[16 * SA], al[16 * SA], hnl[16 * SA];
  __shared__ __align__(16) unsigned short hnT[128 * ST], encT[128 * ST];
  __shared__ float hf[16 * HF];
  __shared__ float xred[4];
  const int tid = threadIdx.x, blk = blockIdx.x, b0 = blk * 16;
  const int w = tid >> 6, l = tid & 63;
  const int n = l & 15, g4 = l >> 4;
  const int c = w * 16 + n;

  // zero transposed tiles (k slots 16..31 stay zero forever)
  for (int i = tid; i < 128 * ST; i += 512) { hnT[i] = 0; encT[i] = 0; }
  {  // load initial h (from k_main0) into hf (fp32) + hl (bf16)
    const int r = tid >> 5, c4 = (tid & 31) << 2;
    float4 hv = ld4(hinit + (size_t)(b0 + r) * DH + c4);
    st4(hf + r * HF + c4, hv);
    unsigned short* hp = hl + r * SA + c4;
    hp[0] = f2b(hv.x); hp[1] = f2b(hv.y); hp[2] = f2b(hv.z); hp[3] = f2b(hv.w);
  }
  const float b2c = att2b[c];
  const float bihR = bih[c], bihZ = bih[DH + c], bihN = bih[2 * DH + c];
  const float bhhR = bhh[c], bhhZ = bhh[DH + c], bhhN = bhh[2 * DH + c];
  const float obc = (w < 2) ? outb[c] : 0.f;
  TileRegs trN;
  const f32x4 z4 = {0.f, 0.f, 0.f, 0.f};

  for (int t = 1; t < NT; ++t) {
    // ---- stage: Wm -> slot0, el(t), encT(t+1); preload a2a
    loadT(trN, Wmb, tid, 1);
    writeT(trN, Wslot[0], tid, 1);
    if (tid < 256) {
      const int r = tid >> 4, c8 = (tid & 15) << 3;
      float4 e0 = ld4(enc + ((size_t)(b0 + r) * NT + t) * DH + c8);
      float4 e1 = ld4(enc + ((size_t)(b0 + r) * NT + t) * DH + c8 + 4);
      unsigned short* ep = el + r * SA + c8;
      ep[0]=f2b(e0.x); ep[1]=f2b(e0.y); ep[2]=f2b(e0.z); ep[3]=f2b(e0.w);
      ep[4]=f2b(e1.x); ep[5]=f2b(e1.y); ep[6]=f2b(e1.z); ep[7]=f2b(e1.w);
    } else if (t < NT - 1) {
      const int idx = tid - 256;
      const int r = idx & 15, c8 = (idx >> 4) << 3;
      float4 e0 = ld4(enc + ((size_t)(b0 + r) * NT + t + 1) * DH + c8);
      float4 e1 = ld4(enc + ((size_t)(b0 + r) * NT + t + 1) * DH + c8 + 4);
      encT[(c8 + 0) * ST + r] = f2b(e0.x); encT[(c8 + 1) * ST + r] = f2b(e0.y);
      encT[(c8 + 2) * ST + r] = f2b(e0.z); encT[(c8 + 3) * ST + r] = f2b(e0.w);
      encT[(c8 + 4) * ST + r] = f2b(e1.x); encT[(c8 + 5) * ST + r] = f2b(e1.y);
      encT[(c8 + 6) * ST + r] = f2b(e1.z); encT[(c8 + 7) * ST + r] = f2b(e1.w);
    }
    loadT(trN, wbf, tid, 1);
    __syncthreads();

    f32x4 aC = z4, aA = z4, aR = z4, aZ = z4, aIN = z4, aHN = z4;
    // ph0: ctx = el @ Wm^T (s0)
    mm16(aC, Wslot[0], el, w, l);
    writeT(trN, Wslot[1], tid, 1); loadT(trN, wbf + 16384, tid, 1);
#pragma unroll
    for (int j = 0; j < 4; ++j) ctxl[(g4 * 4 + j) * SA + c] = f2b(aC[j]);
    __syncthreads();
    // ph1: aA = ctx @ a2a^T (s1)
    mm16(aA, Wslot[1], ctxl, w, l);
    writeT(trN, Wslot[0], tid, 1); loadT(trN, wbf + 2 * 16384, tid, 1);
    __syncthreads();
    // ph2: aA += h @ a2b^T (s0); al = tanh(aA + b2)
    mm16(aA, Wslot[0], hl, w, l);
    writeT(trN, Wslot[1], tid, 1); loadT(trN, wbf + 3 * 16384, tid, 1);
#pragma unroll
    for (int j = 0; j < 4; ++j) al[(g4 * 4 + j) * SA + c] = f2b(tanhf(aA[j] + b2c));
    __syncthreads();
    // ph3: r = al @ wihR^T (s1)
    mm16(aR, Wslot[1], al, w, l);
    writeT(trN, Wslot[0], tid, 1); loadT(trN, wbf + 4 * 16384, tid, 1);
    __syncthreads();
    // ph4: r += h @ whhR^T (s0)
    mm16(aR, Wslot[0], hl, w, l);
    writeT(trN, Wslot[1], tid, 1); loadT(trN, wbf + 5 * 16384, tid, 1);
    __syncthreads();
    // ph5: z = al @ wihZ^T (s1)
    mm16(aZ, Wslot[1], al, w, l);
    writeT(trN, Wslot[0], tid, 1); loadT(trN, wbf + 6 * 16384, tid, 1);
    __syncthreads();
    // ph6: z += h @ whhZ^T (s0)
    mm16(aZ, Wslot[0], hl, w, l);
    writeT(trN, Wslot[1], tid, 1); loadT(trN, wbf + 7 * 16384, tid, 1);
    __syncthreads();
    // ph7: in = al @ wihN^T (s1)
    mm16(aIN, Wslot[1], al, w, l);
    writeT(trN, Wslot[0], tid, 1); loadT(trN, wbf + 8 * 16384, tid, 0);
    __syncthreads();
    // ph8: hn = h @ whhN^T (s0); gates
    mm16(aHN, Wslot[0], hl, w, l);
    writeT(trN, Wslot[1], tid, 0);
    __syncthreads();  // all mm reads of hl done before overwrite
#pragma unroll
    for (int j = 0; j < 4; ++j) {
      const int row = g4 * 4 + j;
      const float rg = sigm(aR[j] + bihR + bhhR);
      const float zg = sigm(aZ[j] + bihZ + bhhZ);
      const float ng = tanhf(aIN[j] + bihN + rg * (aHN[j] + bhhN));
      const float ho = hf[row * HF + c];
      const float hv = (1.f - zg) * ng + zg * ho;
      hf[row * HF + c] = hv;
      const unsigned short hb = f2b(hv);
      hnl[row * SA + c] = hb;
      hl[row * SA + c] = hb;
      hnT[c * ST + row] = hb;
    }
    __syncthreads();
    // ph9: out-proj (waves 0-1) + scores partial for t+1
    if (w < 2) {
      f32x4 aO = z4;
      mm16(aO, Wslot[1], hnl, w, l);
#pragma unroll
      for (int j = 0; j < 4; ++j)
        out[((size_t)(b0 + g4 * 4 + j) * NT + t) * DI + c] = aO[j] + obc;
    }
    if (t < NT - 1) {
      bf16x8 afr = *(const bf16x8*)(hnT + (16 * w + n) * ST + g4 * 8);
      unsigned short* spb = spart + ((size_t)(16 * w + g4 * 4) * 256 + blk) * 128 + n;
#pragma unroll
      for (int nt = 0; nt < 8; ++nt) {
        bf16x8 bfr = *(const bf16x8*)(encT + (16 * nt + n) * ST + g4 * 8);
        f32x4 s = __builtin_amdgcn_mfma_f32_16x16x32_bf16(afr, bfr, z4, 0, 0, 0);
#pragma unroll
        for (int jj = 0; jj < 4; ++jj)
          spb[(size_t)jj * 256 * 128 + nt * 16] = f2b(s[jj]);
      }
      __threadfence();
      grid.sync();
      // ---- distributed softmax: blocks 0..127, row = blk
      if (blk < 128) {
        const unsigned short* sp = spart + (size_t)blk * 256 * 128;
        float* scr = (float*)el;
        const int j = tid & 127, pc = tid >> 7;
        float s = 0.f;
#pragma unroll 8
        for (int p = 0; p < 64; ++p) s += b2f(sp[(size_t)(pc * 64 + p) * 128 + j]);
        scr[pc * 128 + j] = s;
        __syncthreads();
        float sv = 0.f, ev = 0.f;
        if (tid < 128) {
          sv = scr[tid] + scr[128 + tid] + scr[256 + tid] + scr[384 + tid];
          float m = sv;
          for (int o = 1; o < 64; o <<= 1) m = fmaxf(m, __shfl_xor(m, o));
          if ((tid & 63) == 0) xred[tid >> 6] = m;
        }
        __syncthreads();
        if (tid < 128) {
          const float m = fmaxf(xred[0], xred[1]);
          ev = expf(sv - m);
          float sum = ev;
          for (int o = 1; o < 64; o <<= 1) sum += __shfl_xor(sum, o);
          if ((tid & 63) == 0) xred[2 + (tid >> 6)] = sum;
        }
        __syncthreads();
        if (tid < 128) {
          const float sum = xred[2] + xred[3];
          Wmb[blk * 128 + tid] = f2b(ev / sum);
        }
        __threadfence();
      }
      grid.sync();
    }
  }
}

// ============ step-0 path (fp32, runs once) ============
__device__ __forceinline__ void stage128(float* dst, const float* __restrict__ src,
                                         int rows, int srcStride, int tid) {
  const int n4 = rows * 32;
  for (int idx = tid; idx < n4; idx += 512) {
    const int r = idx >> 5, c4 = (idx & 31) << 2;
    st4(dst + r * LDW + c4, ld4(src + (size_t)r * srcStride + c4));
  }
}
template<int ADD>
__device__ __forceinline__ void phase128(float* Wb, const float* act, float* dest, int tid) {
  const int ks = tid & 7, cg_ = (tid >> 3) & 15, r4 = tid >> 7;
  const int rbase = r4 * 4;
  float acc[4][8];
#pragma unroll
  for (int a = 0; a < 4; ++a)
#pragma unroll
    for (int b = 0; b < 8; ++b) acc[a][b] = 0.f;
#pragma unroll
  for (int ch = 0; ch < 4; ++ch) {
    const int k = ks * 4 + ch * 32;
    float4 av[4];
#pragma unroll
    for (int ri = 0; ri < 4; ++ri) av[ri] = ld4(act + (rbase + ri) * LDW + k);
#pragma unroll
    for (int i = 0; i < 8; ++i) {
      float4 wv = ld4(Wb + (cg_ * 8 + i) * LDW + k);
#pragma unroll
      for (int ri = 0; ri < 4; ++ri) acc[ri][i] += dot4(wv, av[ri]);
    }
  }
  __syncthreads();
#pragma unroll
  for (int ri = 0; ri < 4; ++ri) {
    st4(Wb + ks * SCR_KS + (rbase + ri) * LDW + cg_ * 8,
        make_float4(acc[ri][0], acc[ri][1], acc[ri][2], acc[ri][3]));
    st4(Wb + ks * SCR_KS + (rbase + ri) * LDW + cg_ * 8 + 4,
        make_float4(acc[ri][4], acc[ri][5], acc[ri][6], acc[ri][7]));
  }
  __syncthreads();
  const int fr = tid >> 5, fc = (tid & 31) << 2;
  float4 s = make_float4(0.f, 0.f, 0.f, 0.f);
#pragma unroll
  for (int kk = 0; kk < 8; ++kk) {
    float4 v = ld4(Wb + kk * SCR_KS + fr * LDW + fc);
    s.x += v.x; s.y += v.y; s.z += v.z; s.w += v.w;
  }
  float* dp = dest + fr * LDW + fc;
  if (ADD) { float4 o = ld4(dp); s.x += o.x; s.y += o.y; s.z += o.z; s.w += o.w; }
  st4(dp, s);
  __syncthreads();
}
__device__ __forceinline__ void gru_out(float p0, float p1, float p2, float p3,
                                        float bi0, float bi1, float bi2,
                                        float bh0, float bh1, float bh2,
                                        float hv, float* o) {
  const float rg = sigm(p0 + bi0 + bh0);
  const float zg = sigm(p1 + bi1 + bh1);
  const float ng = tanhf(p2 + bi2 + rg * (p3 + bh2));
  *o = (1.f - zg) * ng + zg * hv;
}
__global__ __launch_bounds__(512) void k_main0(
    const float* __restrict__ enc, const float* __restrict__ fcn,
    const float* __restrict__ W0,
    const float* __restrict__ A1, const float* __restrict__ b1,
    const float* __restrict__ wih, const float* __restrict__ whh,
    const float* __restrict__ bih, const float* __restrict__ bhh,
    const float* __restrict__ outw, const float* __restrict__ outb,
    float* __restrict__ h, float* __restrict__ out) {
  __shared__ float Wb[16960];
  __shared__ float el[16 * LDW], hrep[16 * LDW], al[16 * LDW], hn[16 * LDW];
  __shared__ float pre[4][16 * LDW];
  __shared__ float fl[16 * 36];
  const int tid = threadIdx.x, b0 = blockIdx.x * 16;
  {
    const int r = tid >> 5, c4 = (tid & 31) << 2;
    st4(el + r * LDW + c4, ld4(enc + ((size_t)(b0 + r) * NT + 0) * DH + c4));
  }
  {
    const int r = tid >> 5, cc = tid & 31;
    fl[r * 36 + cc] = fcn[(size_t)(b0 + r) * DI + cc];
  }
  __syncthreads();
  {
    const int r = tid >> 5, fc = (tid & 31) << 2;
    st4(hrep + r * LDW + fc, ld4(fl + r * 36 + (fc & 31)));
  }
  stage128(Wb, W0, 32, 128, tid);
  __syncthreads();
  {
    const int r = tid >> 5, q = tid & 31;
    float acc = 0.f;
#pragma unroll 8
    for (int k4 = 0; k4 < 32; ++k4)
      acc += dot4(ld4(Wb + q * LDW + k4 * 4), ld4(el + r * LDW + k4 * 4));
    hn[r * LDW + q] = acc;
  }
  __syncthreads();
  for (int idx = tid; idx < 512; idx += 512) {
    const int r = idx >> 4, c4 = (idx & 15) << 2;
    st4(Wb + r * 68 + c4, ld4(A1 + r * 64 + c4));
  }
  __syncthreads();
  {
    const int r = tid >> 5, i = tid & 31;
    float acc = b1[i];
#pragma unroll
    for (int k4 = 0; k4 < 8; ++k4)
      acc += dot4(ld4(Wb + i * 68 + k4 * 4), ld4(hn + r * LDW + k4 * 4));
#pragma unroll
    for (int k4 = 0; k4 < 8; ++k4)
      acc += dot4(ld4(Wb + i * 68 + 32 + k4 * 4), ld4(fl + r * 36 + k4 * 4));
    al[r * LDW + i] = tanhf(acc);
  }
  __syncthreads();
  for (int idx = tid; idx < 384 * 8; idx += 512) {
    const int r = idx >> 3, c4 = (idx & 7) << 2;
    st4(Wb + r * 36 + c4, ld4(wih + r * 32 + c4));
  }
  __syncthreads();
  {
    const int r = tid >> 5, ccc = tid & 31;
#pragma unroll
    for (int m = 0; m < 12; ++m) {
      const int cc = ccc + 32 * m, g = cc >> 7, col = cc & 127;
      float acc = 0.f;
#pragma unroll
      for (int k4 = 0; k4 < 8; ++k4)
        acc += dot4(ld4(Wb + cc * 36 + k4 * 4), ld4(al + r * LDW + k4 * 4));
      pre[(g == 2) ? 2 : g][r * LDW + col] = acc;
    }
  }
  __syncthreads();
  stage128(Wb, whh, 128, 128, tid);          __syncthreads();
  phase128<1>(Wb, hrep, pre[0], tid);
  stage128(Wb, whh + 16384, 128, 128, tid);  __syncthreads();
  phase128<1>(Wb, hrep, pre[1], tid);
  stage128(Wb, whh + 32768, 128, 128, tid);  __syncthreads();
  phase128<0>(Wb, hrep, pre[3], tid);
  {
    const int fr = tid >> 5, fc = (tid & 31) << 2;
    float4 p0 = ld4(&pre[0][fr * LDW + fc]), p1 = ld4(&pre[1][fr * LDW + fc]);
    float4 p2 = ld4(&pre[2][fr * LDW + fc]), p3 = ld4(&pre[3][fr * LDW + fc]);
    float4 bi0 = ld4(bih + fc), bi1 = ld4(bih + DH + fc), bi2 = ld4(bih + 2 * DH + fc);
    float4 bh0 = ld4(bhh + fc), bh1 = ld4(bhh + DH + fc), bh2 = ld4(bhh + 2 * DH + fc);
    float4 hv = ld4(hrep + fr * LDW + fc);
    float o0, o1, o2, o3;
    gru_out(p0.x, p1.x, p2.x, p3.x, bi0.x, bi1.x, bi2.x, bh0.x, bh1.x, bh2.x, hv.x, &o0);
    gru_out(p0.y, p1.y, p2.y, p3.y, bi0.y, bi1.y, bi2.y, bh0.y, bh1.y, bh2.y, hv.y, &o1);
    gru_out(p0.z, p1.z, p2.z, p3.z, bi0.z, bi1.z, bi2.z, bh0.z, bh1.z, bh2.z, hv.z, &o2);
    gru_out(p0.w, p1.w, p2.w, p3.w, bi0.w, bi1.w, bi2.w, bh0.w, bh1.w, bh2.w, hv.w, &o3);
    float4 hnew = make_float4(o0, o1, o2, o3);
    st4(hn + fr * LDW + fc, hnew);
    st4(h + (size_t)(b0 + fr) * DH + fc, hnew);
  }
  __syncthreads();
  stage128(Wb, outw, 32, 128, tid);
  __syncthreads();
  {
    const int r = tid >> 5, cc = tid & 31;
    float acc = outb[cc];
#pragma unroll 8
    for (int k4 = 0; k4 < 32; ++k4)
      acc += dot4(ld4(Wb + cc * LDW + k4 * 4), ld4(hn + r * LDW + k4 * 4));
    out[((size_t)(b0 + r) * NT + 0) * DI + cc] = acc;
  }
}

extern "C" void kernel_launch(void* const* d_in, const int* in_sizes, int n_in,
                              void* d_out, int out_size, void* d_ws, size_t ws_size,
                              hipStream_t stream) {
  (void)in_sizes; (void)n_in; (void)out_size; (void)ws_size;
  const float* fcn  = (const float*)d_in[0];
  const float* enc  = (const float*)d_in[1];
  const float* a1w  = (const float*)d_in[2];
  const float* a1b  = (const float*)d_in[3];
  const float* a2w  = (const float*)d_in[4];
  const float* a2b  = (const float*)d_in[5];
  const float* w1ih = (const float*)d_in[6];
  const float* w1hh = (const float*)d_in[7];
  const float* b1ih = (const float*)d_in[8];
  const float* b1hh = (const float*)d_in[9];
  const float* w2ih = (const float*)d_in[10];
  const float* w2hh = (const float*)d_in[11];
  const float* b2ih = (const float*)d_in[12];
  const float* b2hh = (const float*)d_in[13];
  const float* outw = (const float*)d_in[14];
  const float* outb = (const float*)d_in[15];
  float* out = (float*)d_out;
  float* ws  = (float*)d_ws;

  float* h        = ws;                                    // 524288 f32
  float* spart32  = ws + 524288;                           // bootstrap partials (<=4MB)
  unsigned short* spartB = (unsigned short*)(ws + 524288); // persist partials bf16 (8.4MB, aliased)
  float* Wbuf = ws + 2621440;                              // 16384 f32
  unsigned short* wbf = (unsigned short*)(ws + 2637824);   // 135168 bf16
  unsigned short* Wmb = (unsigned short*)(ws + 2705408);   // 16384 bf16

  k_prep<<<264, 512, 0, stream>>>(a2w, w2ih, w2hh, outw, wbf);

  // step 0 (fp32 path)
  k_scores<DI><<<64, 512, 0, stream>>>(fcn, enc, 0, spart32);
  k_soft<DI, 64><<<DI, 128, 0, stream>>>(spart32, Wbuf, Wmb);
  k_main0<<<BZ / 16, 512, 0, stream>>>(enc, fcn, Wbuf, a1w, a1b,
                                       w1ih, w1hh, b1ih, b1hh, outw, outb, h, out);
  // bootstrap scores for t=1
  k_scores<DH><<<64, 512, 0, stream>>>(h, enc, 1, spart32);
  k_soft<DH, 64><<<DH, 128, 0, stream>>>(spart32, Wbuf, Wmb);

  // steps 1..127: persistent cooperative kernel
  void* args[] = {
    (void*)&enc, (void*)&Wmb, (void*)&wbf, (void*)&a2b,
    (void*)&b2ih, (void*)&b2hh, (void*)&outb,
    (void*)&h, (void*)&out, (void*)&spartB
  };
  hipLaunchCooperativeKernel((void*)k_persist, dim3(256), dim3(512),
                             args, 0, stream);
}

// Round 6
// 3338.076 us; speedup vs baseline: 6.0268x; 6.0268x over previous
//
#include <hip/hip_runtime.h>
#include <math.h>

#define BZ 4096
#define NT 128
#define DH 128
#define DI 32
#define LDW 132      // padded row stride (floats) for 128-wide fp32 LDS tiles
#define SCR_KS 2116  // scratch per-ks-plane stride (16*132 + 4)
#define SA 136       // bf16 act tile row stride
#define ST 40        // transposed tile stride (shorts)

typedef short bf16x8 __attribute__((ext_vector_type(8)));
typedef float f32x4 __attribute__((ext_vector_type(4)));

__device__ __forceinline__ float4 ld4(const float* p) { return *(const float4*)(p); }
__device__ __forceinline__ void st4(float* p, float4 v) { *(float4*)(p) = v; }
__device__ __forceinline__ float dot4(float4 w, float4 a) {
  return w.x*a.x + w.y*a.y + w.z*a.z + w.w*a.w;
}
__device__ __forceinline__ float sigm(float x) { return 1.f / (1.f + expf(-x)); }
__device__ __forceinline__ unsigned short f2b(float x) {
  unsigned u = __float_as_uint(x);
  u += 0x7FFFu + ((u >> 16) & 1u);
  return (unsigned short)(u >> 16);
}

// ---------------- weight prep: fp32 -> bf16 tiles [a2a|a2b|wihR|whhR|wihZ|whhZ|wihN|whhN|outw]
__global__ __launch_bounds__(512) void k_prep(const float* __restrict__ a2w,
                                              const float* __restrict__ wih,
                                              const float* __restrict__ whh,
                                              const float* __restrict__ outw,
                                              unsigned short* __restrict__ wbf) {
  const int idx = blockIdx.x * 512 + threadIdx.x;
  if (idx >= 147456) return;
  const int tile = idx >> 14, pos = idx & 16383;
  float v;
  if (tile == 0)      v = a2w[(pos >> 7) * 256 + (pos & 127)];
  else if (tile == 1) v = a2w[(pos >> 7) * 256 + 128 + (pos & 127)];
  else if (tile == 2) v = wih[pos];
  else if (tile == 3) v = whh[pos];
  else if (tile == 4) v = wih[16384 + pos];
  else if (tile == 5) v = whh[16384 + pos];
  else if (tile == 6) v = wih[32768 + pos];
  else if (tile == 7) v = whh[32768 + pos];
  else                v = (pos < 4096) ? outw[pos] : 0.f;
  wbf[idx] = f2b(v);
}

// ---------------- bootstrap scores partials: 64 blocks x 64 rows
template<int D>
__global__ __launch_bounds__(512) void k_scores(const float* __restrict__ hsrc,
                                                const float* __restrict__ enc,
                                                int t, float* __restrict__ spart) {
  constexpr int IG = D / 8;
  constexpr int JC = (D == 128) ? 4 : 1;
  constexpr int HS = D + 4;
  __shared__ float hs[64 * HS];
  __shared__ float es[64 * LDW];
  const int p = blockIdx.x, tid = threadIdx.x, b0 = p * 64;
  for (int idx = tid; idx < 64 * (D / 4); idx += 512) {
    const int r = idx / (D / 4), c4 = (idx % (D / 4)) * 4;
    st4(hs + r * HS + c4, ld4(hsrc + (size_t)(b0 + r) * D + c4));
  }
  for (int idx = tid; idx < 64 * 32; idx += 512) {
    const int r = idx >> 5, c4 = (idx & 31) << 2;
    st4(es + r * LDW + c4, ld4(enc + ((size_t)(b0 + r) * NT + t) * DH + c4));
  }
  __syncthreads();
  const int ig = tid % IG, jg = tid / IG;
  const int i0 = ig * 8, j0 = jg * JC;
  float acc[8][JC];
#pragma unroll
  for (int a = 0; a < 8; ++a)
#pragma unroll
    for (int b = 0; b < JC; ++b) acc[a][b] = 0.f;
  for (int b = 0; b < 64; ++b) {
    float4 h0 = ld4(hs + b * HS + i0);
    float4 h1 = ld4(hs + b * HS + i0 + 4);
    float hv[8] = {h0.x, h0.y, h0.z, h0.w, h1.x, h1.y, h1.z, h1.w};
    float ev[JC];
    if (JC == 4) {
      float4 e = ld4(es + b * LDW + j0);
      ev[0] = e.x; ev[1] = e.y; ev[2] = e.z; ev[3] = e.w;
    } else {
      ev[0] = es[b * LDW + j0];
    }
#pragma unroll
    for (int ii = 0; ii < 8; ++ii)
#pragma unroll
      for (int jj = 0; jj < JC; ++jj) acc[ii][jj] += hv[ii] * ev[jj];
  }
#pragma unroll
  for (int ii = 0; ii < 8; ++ii)
#pragma unroll
    for (int jj = 0; jj < JC; ++jj)
      spart[((size_t)p * D + (i0 + ii)) * 128 + j0 + jj] = acc[ii][jj];
}

// ---------------- bootstrap: reduce P partials + row softmax -> fp32 W and bf16 W
template<int R, int P>
__global__ __launch_bounds__(128) void k_soft(const float* __restrict__ spart,
                                              float* __restrict__ W,
                                              unsigned short* __restrict__ Wmb) {
  const int r = blockIdx.x, j = threadIdx.x;
  float s = 0.f;
#pragma unroll 8
  for (int p = 0; p < P; ++p) s += spart[((size_t)p * R + r) * 128 + j];
  __shared__ float xm[2], xs[2];
  float m = s;
  for (int o = 1; o < 64; o <<= 1) m = fmaxf(m, __shfl_xor(m, o));
  if ((j & 63) == 0) xm[j >> 6] = m;
  __syncthreads();
  m = fmaxf(xm[0], xm[1]);
  float e = expf(s - m);
  float sum = e;
  for (int o = 1; o < 64; o <<= 1) sum += __shfl_xor(sum, o);
  if ((j & 63) == 0) xs[j >> 6] = sum;
  __syncthreads();
  sum = xs[0] + xs[1];
  const float val = e / sum;
  W[r * 128 + j] = val;
  Wmb[r * 128 + j] = f2b(val);
}

// ---------------- steady-state softmax: 128 blocks x 512 threads, P=128 partials
__global__ __launch_bounds__(512) void k_soft2(const float* __restrict__ spart,
                                               unsigned short* __restrict__ Wmb) {
  __shared__ float scr[512];
  __shared__ float xred[4];
  const int r = blockIdx.x, tid = threadIdx.x;
  const int j = tid & 127, pc = tid >> 7;
  float s = 0.f;
#pragma unroll 8
  for (int p = pc * 32; p < (pc + 1) * 32; ++p)
    s += spart[((size_t)p * 128 + r) * 128 + j];
  scr[pc * 128 + j] = s;
  __syncthreads();
  if (tid < 128) {
    const float sv = scr[tid] + scr[128 + tid] + scr[256 + tid] + scr[384 + tid];
    float m = sv;
    for (int o = 1; o < 64; o <<= 1) m = fmaxf(m, __shfl_xor(m, o));
    if ((tid & 63) == 0) xred[tid >> 6] = m;
  }
  __syncthreads();
  if (tid < 128) {
    const float sv = scr[tid] + scr[128 + tid] + scr[256 + tid] + scr[384 + tid];
    const float m = fmaxf(xred[0], xred[1]);
    float ev = expf(sv - m);
    float sum = ev;
    for (int o = 1; o < 64; o <<= 1) sum += __shfl_xor(sum, o);
    if ((tid & 63) == 0) xred[2 + (tid >> 6)] = sum;
  }
  __syncthreads();
  if (tid < 128) {
    const float sv = scr[tid] + scr[128 + tid] + scr[256 + tid] + scr[384 + tid];
    const float m = fmaxf(xred[0], xred[1]);
    const float sum = xred[2] + xred[3];
    Wmb[r * 128 + tid] = f2b(expf(sv - m) / sum);
  }
}

// ---------------- register-fragment MFMA helpers
struct WTile { bf16x8 k[4]; };  // 16 VGPR: wave's 16 weight rows x K=128
struct AFrag { bf16x8 k[4]; };  // 16 VGPR: 16 act rows x K=128

__device__ __forceinline__ void loadW(WTile& wt, const unsigned short* __restrict__ base,
                                      int R, int g) {
#pragma unroll
  for (int ks = 0; ks < 4; ++ks)
    wt.k[ks] = *(const bf16x8*)(base + (size_t)R * 128 + ks * 32 + g * 8);
}
__device__ __forceinline__ void loadA(AFrag& a, const unsigned short* act, int n, int g) {
  const char* ab = (const char*)act + n * (2 * SA) + g * 16;
#pragma unroll
  for (int ks = 0; ks < 4; ++ks) a.k[ks] = *(const bf16x8*)(ab + ks * 64);
}
__device__ __forceinline__ void mmrr(f32x4& acc, const AFrag& a, const WTile& w) {
#pragma unroll
  for (int ks = 0; ks < 4; ++ks)
    acc = __builtin_amdgcn_mfma_f32_16x16x32_bf16(a.k[ks], w.k[ks], acc, 0, 0, 0);
}

// ---------------- step t>=1: weights-in-registers, 128 blocks x 32 rows
__global__ __launch_bounds__(512, 2) void k_step2(
    const float* __restrict__ enc, int t, int do_next,
    const unsigned short* __restrict__ Wmb, const unsigned short* __restrict__ wbf,
    const float* __restrict__ att2b,
    const float* __restrict__ bih, const float* __restrict__ bhh,
    const float* __restrict__ outb,
    float* __restrict__ h, float* __restrict__ out, float* __restrict__ spart) {
  __shared__ __align__(16) unsigned short el[32 * SA], hl[32 * SA];
  __shared__ __align__(16) unsigned short ctxl[32 * SA], al[32 * SA], hnl[32 * SA];
  __shared__ __align__(16) unsigned short hnT[128 * ST], encT[128 * ST];
  const int tid = threadIdx.x, b0 = blockIdx.x * 32;
  const int w = tid >> 6, l = tid & 63;
  const int n = l & 15, g4 = l >> 4;
  const int c = w * 16 + n;
  const f32x4 z4 = {0.f, 0.f, 0.f, 0.f};

  // ---- load weight fragments (loop-invariant rows R=c of each tile)
  WTile wWm, wA2a, wA2b, wIR, wHR, wIZ, wHZ, wIN, wHN;
  loadW(wWm, Wmb, c, g4);
  loadW(wA2a, wbf + 0 * 16384, c, g4);
  loadW(wA2b, wbf + 1 * 16384, c, g4);
  loadW(wIR,  wbf + 2 * 16384, c, g4);
  loadW(wHR,  wbf + 3 * 16384, c, g4);
  loadW(wIZ,  wbf + 4 * 16384, c, g4);
  loadW(wHZ,  wbf + 5 * 16384, c, g4);
  loadW(wIN,  wbf + 6 * 16384, c, g4);
  loadW(wHN,  wbf + 7 * 16384, c, g4);

  // ---- stage el, hl (32 rows x 128, bf16)
  {
    const int r = tid >> 4, c8 = (tid & 15) << 3;
    float4 e0 = ld4(enc + ((size_t)(b0 + r) * NT + t) * DH + c8);
    float4 e1 = ld4(enc + ((size_t)(b0 + r) * NT + t) * DH + c8 + 4);
    float4 h0 = ld4(h + (size_t)(b0 + r) * DH + c8);
    float4 h1 = ld4(h + (size_t)(b0 + r) * DH + c8 + 4);
    unsigned short* ep = el + r * SA + c8;
    ep[0]=f2b(e0.x); ep[1]=f2b(e0.y); ep[2]=f2b(e0.z); ep[3]=f2b(e0.w);
    ep[4]=f2b(e1.x); ep[5]=f2b(e1.y); ep[6]=f2b(e1.z); ep[7]=f2b(e1.w);
    unsigned short* hp = hl + r * SA + c8;
    hp[0]=f2b(h0.x); hp[1]=f2b(h0.y); hp[2]=f2b(h0.z); hp[3]=f2b(h0.w);
    hp[4]=f2b(h1.x); hp[5]=f2b(h1.y); hp[6]=f2b(h1.z); hp[7]=f2b(h1.w);
  }
  if (do_next) {  // stage enc[:, t+1] transposed
    const int r = tid & 31, c8 = (tid >> 5) << 3;
    float4 e0 = ld4(enc + ((size_t)(b0 + r) * NT + t + 1) * DH + c8);
    float4 e1 = ld4(enc + ((size_t)(b0 + r) * NT + t + 1) * DH + c8 + 4);
    encT[(c8 + 0) * ST + r] = f2b(e0.x); encT[(c8 + 1) * ST + r] = f2b(e0.y);
    encT[(c8 + 2) * ST + r] = f2b(e0.z); encT[(c8 + 3) * ST + r] = f2b(e0.w);
    encT[(c8 + 4) * ST + r] = f2b(e1.x); encT[(c8 + 5) * ST + r] = f2b(e1.y);
    encT[(c8 + 6) * ST + r] = f2b(e1.z); encT[(c8 + 7) * ST + r] = f2b(e1.w);
  }
  // h_prev in registers (C-layout positions)
  float hprev[2][4];
#pragma unroll
  for (int hh = 0; hh < 2; ++hh)
#pragma unroll
    for (int j = 0; j < 4; ++j)
      hprev[hh][j] = h[(size_t)(b0 + hh * 16 + g4 * 4 + j) * DH + c];
  const float b2c = att2b[c];
  const float bihR = bih[c], bihZ = bih[DH + c], bihN = bih[2 * DH + c];
  const float bhhR = bhh[c], bhhZ = bhh[DH + c], bhhN = bhh[2 * DH + c];
  __syncthreads();

  // ---- ph0: ctx = el @ Wm^T
#pragma unroll
  for (int hh = 0; hh < 2; ++hh) {
    AFrag fE;
    loadA(fE, el + hh * 16 * SA, n, g4);
    f32x4 aC = z4;
    mmrr(aC, fE, wWm);
#pragma unroll
    for (int j = 0; j < 4; ++j) ctxl[(hh * 16 + g4 * 4 + j) * SA + c] = f2b(aC[j]);
  }
  __syncthreads();
  // ---- ph1-2: a = tanh(ctx @ a2a^T + h @ a2b^T + b2)
#pragma unroll
  for (int hh = 0; hh < 2; ++hh) {
    AFrag fC, fH;
    loadA(fC, ctxl + hh * 16 * SA, n, g4);
    loadA(fH, hl + hh * 16 * SA, n, g4);
    f32x4 aA = z4;
    mmrr(aA, fC, wA2a);
    mmrr(aA, fH, wA2b);
#pragma unroll
    for (int j = 0; j < 4; ++j)
      al[(hh * 16 + g4 * 4 + j) * SA + c] = f2b(tanhf(aA[j] + b2c));
  }
  __syncthreads();
  // ---- ph3-8: six GRU matvecs, no barriers (al/hl stable)
  f32x4 aR[2], aZ[2], aIN[2], aHN[2];
#pragma unroll
  for (int hh = 0; hh < 2; ++hh) {
    AFrag fA, fH;
    loadA(fA, al + hh * 16 * SA, n, g4);
    loadA(fH, hl + hh * 16 * SA, n, g4);
    f32x4 tr_ = z4, tz = z4, ti = z4, th = z4;
    mmrr(tr_, fA, wIR); mmrr(tr_, fH, wHR);
    mmrr(tz, fA, wIZ);  mmrr(tz, fH, wHZ);
    mmrr(ti, fA, wIN);  mmrr(th, fH, wHN);
    aR[hh] = tr_; aZ[hh] = tz; aIN[hh] = ti; aHN[hh] = th;
  }
  // ---- gates; h_new -> global + hnl + hnT
#pragma unroll
  for (int hh = 0; hh < 2; ++hh) {
#pragma unroll
    for (int j = 0; j < 4; ++j) {
      const int row = hh * 16 + g4 * 4 + j;
      const float rg = sigm(aR[hh][j] + bihR + bhhR);
      const float zg = sigm(aZ[hh][j] + bihZ + bhhZ);
      const float ng = tanhf(aIN[hh][j] + bihN + rg * (aHN[hh][j] + bhhN));
      const float hv = (1.f - zg) * ng + zg * hprev[hh][j];
      const unsigned short hb = f2b(hv);
      hnl[row * SA + c] = hb;
      hnT[c * ST + row] = hb;
      h[(size_t)(b0 + row) * DH + c] = hv;
    }
  }
  __syncthreads();
  // ---- ph9: out-proj (waves 0-1 hold valid outw rows)
  if (w < 2) {
    WTile wOut;
    loadW(wOut, wbf + 8 * 16384, c, g4);
    const float ob = outb[c];
#pragma unroll
    for (int hh = 0; hh < 2; ++hh) {
      AFrag fO;
      loadA(fO, hnl + hh * 16 * SA, n, g4);
      f32x4 o = z4;
      mmrr(o, fO, wOut);
#pragma unroll
      for (int j = 0; j < 4; ++j)
        out[((size_t)(b0 + hh * 16 + g4 * 4 + j) * NT + t) * DI + c] = o[j] + ob;
    }
  }
  // ---- ph10: scores partial for t+1 (K=32 over this block's batch rows)
  if (do_next) {
    bf16x8 afr = *(const bf16x8*)(hnT + (16 * w + n) * ST + g4 * 8);
    float* spb = spart + ((size_t)blockIdx.x * 128 + 16 * w + g4 * 4) * 128 + n;
#pragma unroll
    for (int nt = 0; nt < 8; ++nt) {
      bf16x8 bfr = *(const bf16x8*)(encT + (16 * nt + n) * ST + g4 * 8);
      f32x4 s = __builtin_amdgcn_mfma_f32_16x16x32_bf16(afr, bfr, z4, 0, 0, 0);
#pragma unroll
      for (int jj = 0; jj < 4; ++jj) spb[(size_t)jj * 128 + 16 * nt] = s[jj];
    }
  }
}

// ============ step-0 path (fp32, runs once) ============
__device__ __forceinline__ void stage128(float* dst, const float* __restrict__ src,
                                         int rows, int srcStride, int tid) {
  const int n4 = rows * 32;
  for (int idx = tid; idx < n4; idx += 512) {
    const int r = idx >> 5, c4 = (idx & 31) << 2;
    st4(dst + r * LDW + c4, ld4(src + (size_t)r * srcStride + c4));
  }
}
template<int ADD>
__device__ __forceinline__ void phase128(float* Wb, const float* act, float* dest, int tid) {
  const int ks = tid & 7, cg_ = (tid >> 3) & 15, r4 = tid >> 7;
  const int rbase = r4 * 4;
  float acc[4][8];
#pragma unroll
  for (int a = 0; a < 4; ++a)
#pragma unroll
    for (int b = 0; b < 8; ++b) acc[a][b] = 0.f;
#pragma unroll
  for (int ch = 0; ch < 4; ++ch) {
    const int k = ks * 4 + ch * 32;
    float4 av[4];
#pragma unroll
    for (int ri = 0; ri < 4; ++ri) av[ri] = ld4(act + (rbase + ri) * LDW + k);
#pragma unroll
    for (int i = 0; i < 8; ++i) {
      float4 wv = ld4(Wb + (cg_ * 8 + i) * LDW + k);
#pragma unroll
      for (int ri = 0; ri < 4; ++ri) acc[ri][i] += dot4(wv, av[ri]);
    }
  }
  __syncthreads();
#pragma unroll
  for (int ri = 0; ri < 4; ++ri) {
    st4(Wb + ks * SCR_KS + (rbase + ri) * LDW + cg_ * 8,
        make_float4(acc[ri][0], acc[ri][1], acc[ri][2], acc[ri][3]));
    st4(Wb + ks * SCR_KS + (rbase + ri) * LDW + cg_ * 8 + 4,
        make_float4(acc[ri][4], acc[ri][5], acc[ri][6], acc[ri][7]));
  }
  __syncthreads();
  const int fr = tid >> 5, fc = (tid & 31) << 2;
  float4 s = make_float4(0.f, 0.f, 0.f, 0.f);
#pragma unroll
  for (int kk = 0; kk < 8; ++kk) {
    float4 v = ld4(Wb + kk * SCR_KS + fr * LDW + fc);
    s.x += v.x; s.y += v.y; s.z += v.z; s.w += v.w;
  }
  float* dp = dest + fr * LDW + fc;
  if (ADD) { float4 o = ld4(dp); s.x += o.x; s.y += o.y; s.z += o.z; s.w += o.w; }
  st4(dp, s);
  __syncthreads();
}
__device__ __forceinline__ void gru_out(float p0, float p1, float p2, float p3,
                                        float bi0, float bi1, float bi2,
                                        float bh0, float bh1, float bh2,
                                        float hv, float* o) {
  const float rg = sigm(p0 + bi0 + bh0);
  const float zg = sigm(p1 + bi1 + bh1);
  const float ng = tanhf(p2 + bi2 + rg * (p3 + bh2));
  *o = (1.f - zg) * ng + zg * hv;
}
__global__ __launch_bounds__(512) void k_main0(
    const float* __restrict__ enc, const float* __restrict__ fcn,
    const float* __restrict__ W0,
    const float* __restrict__ A1, const float* __restrict__ b1,
    const float* __restrict__ wih, const float* __restrict__ whh,
    const float* __restrict__ bih, const float* __restrict__ bhh,
    const float* __restrict__ outw, const float* __restrict__ outb,
    float* __restrict__ h, float* __restrict__ out) {
  __shared__ float Wb[16960];
  __shared__ float el[16 * LDW], hrep[16 * LDW], al[16 * LDW], hn[16 * LDW];
  __shared__ float pre[4][16 * LDW];
  __shared__ float fl[16 * 36];
  const int tid = threadIdx.x, b0 = blockIdx.x * 16;
  {
    const int r = tid >> 5, c4 = (tid & 31) << 2;
    st4(el + r * LDW + c4, ld4(enc + ((size_t)(b0 + r) * NT + 0) * DH + c4));
  }
  {
    const int r = tid >> 5, cc = tid & 31;
    fl[r * 36 + cc] = fcn[(size_t)(b0 + r) * DI + cc];
  }
  __syncthreads();
  {
    const int r = tid >> 5, fc = (tid & 31) << 2;
    st4(hrep + r * LDW + fc, ld4(fl + r * 36 + (fc & 31)));
  }
  stage128(Wb, W0, 32, 128, tid);
  __syncthreads();
  {
    const int r = tid >> 5, q = tid & 31;
    float acc = 0.f;
#pragma unroll 8
    for (int k4 = 0; k4 < 32; ++k4)
      acc += dot4(ld4(Wb + q * LDW + k4 * 4), ld4(el + r * LDW + k4 * 4));
    hn[r * LDW + q] = acc;
  }
  __syncthreads();
  for (int idx = tid; idx < 512; idx += 512) {
    const int r = idx >> 4, c4 = (idx & 15) << 2;
    st4(Wb + r * 68 + c4, ld4(A1 + r * 64 + c4));
  }
  __syncthreads();
  {
    const int r = tid >> 5, i = tid & 31;
    float acc = b1[i];
#pragma unroll
    for (int k4 = 0; k4 < 8; ++k4)
      acc += dot4(ld4(Wb + i * 68 + k4 * 4), ld4(hn + r * LDW + k4 * 4));
#pragma unroll
    for (int k4 = 0; k4 < 8; ++k4)
      acc += dot4(ld4(Wb + i * 68 + 32 + k4 * 4), ld4(fl + r * 36 + k4 * 4));
    al[r * LDW + i] = tanhf(acc);
  }
  __syncthreads();
  for (int idx = tid; idx < 384 * 8; idx += 512) {
    const int r = idx >> 3, c4 = (idx & 7) << 2;
    st4(Wb + r * 36 + c4, ld4(wih + r * 32 + c4));
  }
  __syncthreads();
  {
    const int r = tid >> 5, ccc = tid & 31;
#pragma unroll
    for (int m = 0; m < 12; ++m) {
      const int cc = ccc + 32 * m, g = cc >> 7, col = cc & 127;
      float acc = 0.f;
#pragma unroll
      for (int k4 = 0; k4 < 8; ++k4)
        acc += dot4(ld4(Wb + cc * 36 + k4 * 4), ld4(al + r * LDW + k4 * 4));
      pre[(g == 2) ? 2 : g][r * LDW + col] = acc;
    }
  }
  __syncthreads();
  stage128(Wb, whh, 128, 128, tid);          __syncthreads();
  phase128<1>(Wb, hrep, pre[0], tid);
  stage128(Wb, whh + 16384, 128, 128, tid);  __syncthreads();
  phase128<1>(Wb, hrep, pre[1], tid);
  stage128(Wb, whh + 32768, 128, 128, tid);  __syncthreads();
  phase128<0>(Wb, hrep, pre[3], tid);
  {
    const int fr = tid >> 5, fc = (tid & 31) << 2;
    float4 p0 = ld4(&pre[0][fr * LDW + fc]), p1 = ld4(&pre[1][fr * LDW + fc]);
    float4 p2 = ld4(&pre[2][fr * LDW + fc]), p3 = ld4(&pre[3][fr * LDW + fc]);
    float4 bi0 = ld4(bih + fc), bi1 = ld4(bih + DH + fc), bi2 = ld4(bih + 2 * DH + fc);
    float4 bh0 = ld4(bhh + fc), bh1 = ld4(bhh + DH + fc), bh2 = ld4(bhh + 2 * DH + fc);
    float4 hv = ld4(hrep + fr * LDW + fc);
    float o0, o1, o2, o3;
    gru_out(p0.x, p1.x, p2.x, p3.x, bi0.x, bi1.x, bi2.x, bh0.x, bh1.x, bh2.x, hv.x, &o0);
    gru_out(p0.y, p1.y, p2.y, p3.y, bi0.y, bi1.y, bi2.y, bh0.y, bh1.y, bh2.y, hv.y, &o1);
    gru_out(p0.z, p1.z, p2.z, p3.z, bi0.z, bi1.z, bi2.z, bh0.z, bh1.z, bh2.z, hv.z, &o2);
    gru_out(p0.w, p1.w, p2.w, p3.w, bi0.w, bi1.w, bi2.w, bh0.w, bh1.w, bh2.w, hv.w, &o3);
    float4 hnew = make_float4(o0, o1, o2, o3);
    st4(hn + fr * LDW + fc, hnew);
    st4(h + (size_t)(b0 + fr) * DH + fc, hnew);
  }
  __syncthreads();
  stage128(Wb, outw, 32, 128, tid);
  __syncthreads();
  {
    const int r = tid >> 5, cc = tid & 31;
    float acc = outb[cc];
#pragma unroll 8
    for (int k4 = 0; k4 < 32; ++k4)
      acc += dot4(ld4(Wb + cc * LDW + k4 * 4), ld4(hn + r * LDW + k4 * 4));
    out[((size_t)(b0 + r) * NT + 0) * DI + cc] = acc;
  }
}

extern "C" void kernel_launch(void* const* d_in, const int* in_sizes, int n_in,
                              void* d_out, int out_size, void* d_ws, size_t ws_size,
                              hipStream_t stream) {
  (void)in_sizes; (void)n_in; (void)out_size; (void)ws_size;
  const float* fcn  = (const float*)d_in[0];
  const float* enc  = (const float*)d_in[1];
  const float* a1w  = (const float*)d_in[2];
  const float* a1b  = (const float*)d_in[3];
  const float* a2w  = (const float*)d_in[4];
  const float* a2b  = (const float*)d_in[5];
  const float* w1ih = (const float*)d_in[6];
  const float* w1hh = (const float*)d_in[7];
  const float* b1ih = (const float*)d_in[8];
  const float* b1hh = (const float*)d_in[9];
  const float* w2ih = (const float*)d_in[10];
  const float* w2hh = (const float*)d_in[11];
  const float* b2ih = (const float*)d_in[12];
  const float* b2hh = (const float*)d_in[13];
  const float* outw = (const float*)d_in[14];
  const float* outb = (const float*)d_in[15];
  float* out = (float*)d_out;
  float* ws  = (float*)d_ws;

  float* h     = ws;                                       // 524288 f32
  float* spart = ws + 524288;                              // up to 128*128*128 f32 (8 MB)
  float* Wbuf  = ws + 2621440;                             // 16384 f32
  unsigned short* wbf = (unsigned short*)(ws + 2637824);   // 147456 bf16
  unsigned short* Wmb = (unsigned short*)(ws + 2712576);   // 16384 bf16

  k_prep<<<288, 512, 0, stream>>>(a2w, w2ih, w2hh, outw, wbf);

  // step 0 (fp32 path)
  k_scores<DI><<<64, 512, 0, stream>>>(fcn, enc, 0, spart);
  k_soft<DI, 64><<<DI, 128, 0, stream>>>(spart, Wbuf, Wmb);
  k_main0<<<BZ / 16, 512, 0, stream>>>(enc, fcn, Wbuf, a1w, a1b,
                                       w1ih, w1hh, b1ih, b1hh, outw, outb, h, out);
  // bootstrap scores for t=1
  k_scores<DH><<<64, 512, 0, stream>>>(h, enc, 1, spart);
  k_soft<DH, 64><<<DH, 128, 0, stream>>>(spart, Wbuf, Wmb);

  // steps 1..127 (fused, weights-in-registers)
  for (int t = 1; t < NT; ++t) {
    const int do_next = (t < NT - 1) ? 1 : 0;
    k_step2<<<128, 512, 0, stream>>>(enc, t, do_next, Wmb, wbf, a2b,
                                     b2ih, b2hh, outb, h, out, spart);
    if (do_next)
      k_soft2<<<128, 512, 0, stream>>>(spart, Wmb);
  }
}

// Round 7
// 3241.588 us; speedup vs baseline: 6.2062x; 1.0298x over previous
//
#include <hip/hip_runtime.h>
#include <math.h>

#define BZ 4096
#define NT 128
#define DH 128
#define DI 32
#define LDW 132      // padded row stride (floats) for 128-wide fp32 LDS tiles
#define SCR_KS 2116  // scratch per-ks-plane stride (16*132 + 4)
#define SA 136       // bf16 act tile row stride
#define ST 40        // transposed tile stride (shorts)

typedef short bf16x8 __attribute__((ext_vector_type(8)));
typedef float f32x4 __attribute__((ext_vector_type(4)));

__device__ __forceinline__ float4 ld4(const float* p) { return *(const float4*)(p); }
__device__ __forceinline__ void st4(float* p, float4 v) { *(float4*)(p) = v; }
__device__ __forceinline__ float dot4(float4 w, float4 a) {
  return w.x*a.x + w.y*a.y + w.z*a.z + w.w*a.w;
}
__device__ __forceinline__ float sigm(float x) { return 1.f / (1.f + expf(-x)); }
__device__ __forceinline__ unsigned short f2b(float x) {
  unsigned u = __float_as_uint(x);
  u += 0x7FFFu + ((u >> 16) & 1u);
  return (unsigned short)(u >> 16);
}

// ---------------- weight prep: fp32 -> bf16 tiles [a2a|a2b|wihR|whhR|wihZ|whhZ|wihN|whhN|outw]
__global__ __launch_bounds__(512) void k_prep(const float* __restrict__ a2w,
                                              const float* __restrict__ wih,
                                              const float* __restrict__ whh,
                                              const float* __restrict__ outw,
                                              unsigned short* __restrict__ wbf) {
  const int idx = blockIdx.x * 512 + threadIdx.x;
  if (idx >= 147456) return;
  const int tile = idx >> 14, pos = idx & 16383;
  float v;
  if (tile == 0)      v = a2w[(pos >> 7) * 256 + (pos & 127)];
  else if (tile == 1) v = a2w[(pos >> 7) * 256 + 128 + (pos & 127)];
  else if (tile == 2) v = wih[pos];
  else if (tile == 3) v = whh[pos];
  else if (tile == 4) v = wih[16384 + pos];
  else if (tile == 5) v = whh[16384 + pos];
  else if (tile == 6) v = wih[32768 + pos];
  else if (tile == 7) v = whh[32768 + pos];
  else                v = (pos < 4096) ? outw[pos] : 0.f;
  wbf[idx] = f2b(v);
}

// ---------------- bootstrap scores partials: 64 blocks x 64 rows
template<int D>
__global__ __launch_bounds__(512) void k_scores(const float* __restrict__ hsrc,
                                                const float* __restrict__ enc,
                                                int t, float* __restrict__ spart) {
  constexpr int IG = D / 8;
  constexpr int JC = (D == 128) ? 4 : 1;
  constexpr int HS = D + 4;
  __shared__ float hs[64 * HS];
  __shared__ float es[64 * LDW];
  const int p = blockIdx.x, tid = threadIdx.x, b0 = p * 64;
  for (int idx = tid; idx < 64 * (D / 4); idx += 512) {
    const int r = idx / (D / 4), c4 = (idx % (D / 4)) * 4;
    st4(hs + r * HS + c4, ld4(hsrc + (size_t)(b0 + r) * D + c4));
  }
  for (int idx = tid; idx < 64 * 32; idx += 512) {
    const int r = idx >> 5, c4 = (idx & 31) << 2;
    st4(es + r * LDW + c4, ld4(enc + ((size_t)(b0 + r) * NT + t) * DH + c4));
  }
  __syncthreads();
  const int ig = tid % IG, jg = tid / IG;
  const int i0 = ig * 8, j0 = jg * JC;
  float acc[8][JC];
#pragma unroll
  for (int a = 0; a < 8; ++a)
#pragma unroll
    for (int b = 0; b < JC; ++b) acc[a][b] = 0.f;
  for (int b = 0; b < 64; ++b) {
    float4 h0 = ld4(hs + b * HS + i0);
    float4 h1 = ld4(hs + b * HS + i0 + 4);
    float hv[8] = {h0.x, h0.y, h0.z, h0.w, h1.x, h1.y, h1.z, h1.w};
    float ev[JC];
    if (JC == 4) {
      float4 e = ld4(es + b * LDW + j0);
      ev[0] = e.x; ev[1] = e.y; ev[2] = e.z; ev[3] = e.w;
    } else {
      ev[0] = es[b * LDW + j0];
    }
#pragma unroll
    for (int ii = 0; ii < 8; ++ii)
#pragma unroll
      for (int jj = 0; jj < JC; ++jj) acc[ii][jj] += hv[ii] * ev[jj];
  }
#pragma unroll
  for (int ii = 0; ii < 8; ++ii)
#pragma unroll
    for (int jj = 0; jj < JC; ++jj)
      spart[((size_t)p * D + (i0 + ii)) * 128 + j0 + jj] = acc[ii][jj];
}

// ---------------- bootstrap: reduce P partials + row softmax -> fp32 W (+bf16)
template<int R, int P>
__global__ __launch_bounds__(128) void k_soft(const float* __restrict__ spart,
                                              float* __restrict__ W,
                                              unsigned short* __restrict__ Wmb) {
  const int r = blockIdx.x, j = threadIdx.x;
  float s = 0.f;
#pragma unroll 8
  for (int p = 0; p < P; ++p) s += spart[((size_t)p * R + r) * 128 + j];
  __shared__ float xm[2], xs[2];
  float m = s;
  for (int o = 1; o < 64; o <<= 1) m = fmaxf(m, __shfl_xor(m, o));
  if ((j & 63) == 0) xm[j >> 6] = m;
  __syncthreads();
  m = fmaxf(xm[0], xm[1]);
  float e = expf(s - m);
  float sum = e;
  for (int o = 1; o < 64; o <<= 1) sum += __shfl_xor(sum, o);
  if ((j & 63) == 0) xs[j >> 6] = sum;
  __syncthreads();
  sum = xs[0] + xs[1];
  const float val = e / sum;
  W[r * 128 + j] = val;
  Wmb[r * 128 + j] = f2b(val);
}

// ---------------- bootstrap: sum 64 partials -> raw S1; zero S2
__global__ __launch_bounds__(128) void k_sum(const float* __restrict__ spart,
                                             float* __restrict__ S1,
                                             float* __restrict__ S2) {
  const int r = blockIdx.x, j = threadIdx.x;
  float s = 0.f;
#pragma unroll 8
  for (int p = 0; p < 64; ++p) s += spart[((size_t)p * 128 + r) * 128 + j];
  S1[r * 128 + j] = s;
  S2[r * 128 + j] = 0.f;
}

// ---------------- register-fragment MFMA helpers
struct WTile { bf16x8 k[4]; };
struct AFrag { bf16x8 k[4]; };

__device__ __forceinline__ void loadW(WTile& wt, const unsigned short* __restrict__ base,
                                      int R, int g) {
#pragma unroll
  for (int ks = 0; ks < 4; ++ks)
    wt.k[ks] = *(const bf16x8*)(base + (size_t)R * 128 + ks * 32 + g * 8);
}
__device__ __forceinline__ void loadA(AFrag& a, const unsigned short* act, int n, int g) {
  const char* ab = (const char*)act + n * (2 * SA) + g * 16;
#pragma unroll
  for (int ks = 0; ks < 4; ++ks) a.k[ks] = *(const bf16x8*)(ab + ks * 64);
}
__device__ __forceinline__ void mmrr(f32x4& acc, const AFrag& a, const WTile& w) {
#pragma unroll
  for (int ks = 0; ks < 4; ++ks)
    acc = __builtin_amdgcn_mfma_f32_16x16x32_bf16(a.k[ks], w.k[ks], acc, 0, 0, 0);
}
// mm from swizzled LDS W tile (phase-A product)
__device__ __forceinline__ void mmls(f32x4& acc, const unsigned short* Wt,
                                     const unsigned short* act, int R, int n, int g) {
  const char* ab = (const char*)act + n * (2 * SA) + g * 16;
  const char* wb = (const char*)Wt;
  const int sw = (R & 7) << 4;
#pragma unroll
  for (int ks = 0; ks < 4; ++ks) {
    bf16x8 b = *(const bf16x8*)(wb + ((R * 256 + ks * 64 + g * 16) ^ sw));
    bf16x8 a = *(const bf16x8*)(ab + ks * 64);
    acc = __builtin_amdgcn_mfma_f32_16x16x32_bf16(a, b, acc, 0, 0, 0);
  }
}

// ---------------- fused step t>=1: softmax(Sread) -> attend -> GRU -> out + S-accum
__global__ __launch_bounds__(512, 2) void k_step3(
    const float* __restrict__ enc, int t, int do_next,
    const float* __restrict__ Srd, float* __restrict__ Sac, float* __restrict__ Szr,
    const unsigned short* __restrict__ wbf,
    const float* __restrict__ att2b,
    const float* __restrict__ bih, const float* __restrict__ bhh,
    const float* __restrict__ outb,
    float* __restrict__ h, float* __restrict__ out) {
  __shared__ __align__(16) unsigned short Wslot[16384];
  __shared__ __align__(16) unsigned short el[32 * SA], hl[32 * SA];
  __shared__ __align__(16) unsigned short ctxl[32 * SA], al[32 * SA], hnl[32 * SA];
  __shared__ __align__(16) unsigned short hnT[128 * ST], encT[128 * ST];
  const int tid = threadIdx.x, b0 = blockIdx.x * 32;
  const int w = tid >> 6, l = tid & 63;
  const int n = l & 15, g4 = l >> 4;
  const int c = w * 16 + n;
  const f32x4 z4 = {0.f, 0.f, 0.f, 0.f};

  // ---- phase A: softmax(Srd) -> Wslot (swizzled bf16, writeT-compatible layout)
  {
    const int row = tid >> 2, q = tid & 3;
    const float* sr = Srd + row * 128 + q * 32;
    float4 v[8];
    float mx = -1e30f;
#pragma unroll
    for (int i = 0; i < 8; ++i) {
      v[i] = ld4(sr + 4 * i);
      mx = fmaxf(mx, fmaxf(fmaxf(v[i].x, v[i].y), fmaxf(v[i].z, v[i].w)));
    }
    mx = fmaxf(mx, __shfl_xor(mx, 1));
    mx = fmaxf(mx, __shfl_xor(mx, 2));
    float sum = 0.f;
#pragma unroll
    for (int i = 0; i < 8; ++i) {
      v[i].x = expf(v[i].x - mx); v[i].y = expf(v[i].y - mx);
      v[i].z = expf(v[i].z - mx); v[i].w = expf(v[i].w - mx);
      sum += (v[i].x + v[i].y) + (v[i].z + v[i].w);
    }
    sum += __shfl_xor(sum, 1);
    sum += __shfl_xor(sum, 2);
    const float inv = 1.f / sum;
    char* wb = (char*)Wslot;
    const int sw = (row & 7) << 4;
#pragma unroll
    for (int ch = 0; ch < 4; ++ch) {
      unsigned short h8[8] = {
        f2b(v[2*ch].x * inv),   f2b(v[2*ch].y * inv),
        f2b(v[2*ch].z * inv),   f2b(v[2*ch].w * inv),
        f2b(v[2*ch+1].x * inv), f2b(v[2*ch+1].y * inv),
        f2b(v[2*ch+1].z * inv), f2b(v[2*ch+1].w * inv)
      };
      *(uint4*)(wb + ((row * 256 + q * 64 + ch * 16) ^ sw)) = *(const uint4*)h8;
    }
  }

  // ---- stage el, hl (32 rows x 128, bf16)
  {
    const int r = tid >> 4, c8 = (tid & 15) << 3;
    float4 e0 = ld4(enc + ((size_t)(b0 + r) * NT + t) * DH + c8);
    float4 e1 = ld4(enc + ((size_t)(b0 + r) * NT + t) * DH + c8 + 4);
    float4 h0 = ld4(h + (size_t)(b0 + r) * DH + c8);
    float4 h1 = ld4(h + (size_t)(b0 + r) * DH + c8 + 4);
    unsigned short e8[8] = {f2b(e0.x), f2b(e0.y), f2b(e0.z), f2b(e0.w),
                            f2b(e1.x), f2b(e1.y), f2b(e1.z), f2b(e1.w)};
    unsigned short h8[8] = {f2b(h0.x), f2b(h0.y), f2b(h0.z), f2b(h0.w),
                            f2b(h1.x), f2b(h1.y), f2b(h1.z), f2b(h1.w)};
    *(uint4*)(el + r * SA + c8) = *(const uint4*)e8;
    *(uint4*)(hl + r * SA + c8) = *(const uint4*)h8;
  }
  if (do_next) {  // stage enc[:, t+1] transposed
    const int r = tid & 31, c8 = (tid >> 5) << 3;
    float4 e0 = ld4(enc + ((size_t)(b0 + r) * NT + t + 1) * DH + c8);
    float4 e1 = ld4(enc + ((size_t)(b0 + r) * NT + t + 1) * DH + c8 + 4);
    encT[(c8 + 0) * ST + r] = f2b(e0.x); encT[(c8 + 1) * ST + r] = f2b(e0.y);
    encT[(c8 + 2) * ST + r] = f2b(e0.z); encT[(c8 + 3) * ST + r] = f2b(e0.w);
    encT[(c8 + 4) * ST + r] = f2b(e1.x); encT[(c8 + 5) * ST + r] = f2b(e1.y);
    encT[(c8 + 6) * ST + r] = f2b(e1.z); encT[(c8 + 7) * ST + r] = f2b(e1.w);
  }
  // zero the buffer two steps ahead (safe: separated by >=1 kernel boundary)
  if (do_next && tid < 128) Szr[blockIdx.x * 128 + tid] = 0.f;

  // ---- static weight fragments in registers
  WTile wA2a, wA2b, wIR, wHR, wIZ, wHZ, wIN, wHN;
  loadW(wA2a, wbf + 0 * 16384, c, g4);
  loadW(wA2b, wbf + 1 * 16384, c, g4);
  loadW(wIR,  wbf + 2 * 16384, c, g4);
  loadW(wHR,  wbf + 3 * 16384, c, g4);
  loadW(wIZ,  wbf + 4 * 16384, c, g4);
  loadW(wHZ,  wbf + 5 * 16384, c, g4);
  loadW(wIN,  wbf + 6 * 16384, c, g4);
  loadW(wHN,  wbf + 7 * 16384, c, g4);

  float hprev[2][4];
#pragma unroll
  for (int hh = 0; hh < 2; ++hh)
#pragma unroll
    for (int j = 0; j < 4; ++j)
      hprev[hh][j] = h[(size_t)(b0 + hh * 16 + g4 * 4 + j) * DH + c];
  const float b2c = att2b[c];
  const float bihR = bih[c], bihZ = bih[DH + c], bihN = bih[2 * DH + c];
  const float bhhR = bhh[c], bhhZ = bhh[DH + c], bhhN = bhh[2 * DH + c];
  __syncthreads();

  // ---- ph0: ctx = el @ W^T  (W from LDS Wslot)
#pragma unroll
  for (int hh = 0; hh < 2; ++hh) {
    f32x4 aC = z4;
    mmls(aC, Wslot, el + hh * 16 * SA, c, n, g4);
#pragma unroll
    for (int j = 0; j < 4; ++j) ctxl[(hh * 16 + g4 * 4 + j) * SA + c] = f2b(aC[j]);
  }
  __syncthreads();
  // ---- ph1-2: a = tanh(ctx @ a2a^T + h @ a2b^T + b2)
#pragma unroll
  for (int hh = 0; hh < 2; ++hh) {
    AFrag fC, fH;
    loadA(fC, ctxl + hh * 16 * SA, n, g4);
    loadA(fH, hl + hh * 16 * SA, n, g4);
    f32x4 aA = z4;
    mmrr(aA, fC, wA2a);
    mmrr(aA, fH, wA2b);
#pragma unroll
    for (int j = 0; j < 4; ++j)
      al[(hh * 16 + g4 * 4 + j) * SA + c] = f2b(tanhf(aA[j] + b2c));
  }
  __syncthreads();
  // ---- ph3-8: six GRU matvecs (al/hl stable, no barriers)
  f32x4 aR[2], aZ[2], aIN[2], aHN[2];
#pragma unroll
  for (int hh = 0; hh < 2; ++hh) {
    AFrag fA, fH;
    loadA(fA, al + hh * 16 * SA, n, g4);
    loadA(fH, hl + hh * 16 * SA, n, g4);
    f32x4 tr_ = z4, tz = z4, ti = z4, th = z4;
    mmrr(tr_, fA, wIR); mmrr(tr_, fH, wHR);
    mmrr(tz, fA, wIZ);  mmrr(tz, fH, wHZ);
    mmrr(ti, fA, wIN);  mmrr(th, fH, wHN);
    aR[hh] = tr_; aZ[hh] = tz; aIN[hh] = ti; aHN[hh] = th;
  }
  // ---- gates; h_new -> global + hnl + hnT
#pragma unroll
  for (int hh = 0; hh < 2; ++hh) {
#pragma unroll
    for (int j = 0; j < 4; ++j) {
      const int row = hh * 16 + g4 * 4 + j;
      const float rg = sigm(aR[hh][j] + bihR + bhhR);
      const float zg = sigm(aZ[hh][j] + bihZ + bhhZ);
      const float ng = tanhf(aIN[hh][j] + bihN + rg * (aHN[hh][j] + bhhN));
      const float hv = (1.f - zg) * ng + zg * hprev[hh][j];
      const unsigned short hb = f2b(hv);
      hnl[row * SA + c] = hb;
      hnT[c * ST + row] = hb;
      h[(size_t)(b0 + row) * DH + c] = hv;
    }
  }
  __syncthreads();
  // ---- ph9: out-proj (waves 0-1)
  if (w < 2) {
    WTile wOut;
    loadW(wOut, wbf + 8 * 16384, c, g4);
    const float ob = outb[c];
#pragma unroll
    for (int hh = 0; hh < 2; ++hh) {
      AFrag fO;
      loadA(fO, hnl + hh * 16 * SA, n, g4);
      f32x4 o = z4;
      mmrr(o, fO, wOut);
#pragma unroll
      for (int j = 0; j < 4; ++j)
        out[((size_t)(b0 + hh * 16 + g4 * 4 + j) * NT + t) * DI + c] = o[j] + ob;
    }
  }
  // ---- ph10: scores partial for t+1 -> atomicAdd into Sac
  if (do_next) {
    bf16x8 afr = *(const bf16x8*)(hnT + (16 * w + n) * ST + g4 * 8);
    float* Sn = Sac + (size_t)(16 * w + g4 * 4) * 128 + n;
#pragma unroll
    for (int nt = 0; nt < 8; ++nt) {
      bf16x8 bfr = *(const bf16x8*)(encT + (16 * nt + n) * ST + g4 * 8);
      f32x4 s = __builtin_amdgcn_mfma_f32_16x16x32_bf16(afr, bfr, z4, 0, 0, 0);
#pragma unroll
      for (int jj = 0; jj < 4; ++jj) atomicAdd(Sn + jj * 128 + nt * 16, s[jj]);
    }
  }
}

// ============ step-0 path (fp32, runs once) ============
__device__ __forceinline__ void stage128(float* dst, const float* __restrict__ src,
                                         int rows, int srcStride, int tid) {
  const int n4 = rows * 32;
  for (int idx = tid; idx < n4; idx += 512) {
    const int r = idx >> 5, c4 = (idx & 31) << 2;
    st4(dst + r * LDW + c4, ld4(src + (size_t)r * srcStride + c4));
  }
}
template<int ADD>
__device__ __forceinline__ void phase128(float* Wb, const float* act, float* dest, int tid) {
  const int ks = tid & 7, cg_ = (tid >> 3) & 15, r4 = tid >> 7;
  const int rbase = r4 * 4;
  float acc[4][8];
#pragma unroll
  for (int a = 0; a < 4; ++a)
#pragma unroll
    for (int b = 0; b < 8; ++b) acc[a][b] = 0.f;
#pragma unroll
  for (int ch = 0; ch < 4; ++ch) {
    const int k = ks * 4 + ch * 32;
    float4 av[4];
#pragma unroll
    for (int ri = 0; ri < 4; ++ri) av[ri] = ld4(act + (rbase + ri) * LDW + k);
#pragma unroll
    for (int i = 0; i < 8; ++i) {
      float4 wv = ld4(Wb + (cg_ * 8 + i) * LDW + k);
#pragma unroll
      for (int ri = 0; ri < 4; ++ri) acc[ri][i] += dot4(wv, av[ri]);
    }
  }
  __syncthreads();
#pragma unroll
  for (int ri = 0; ri < 4; ++ri) {
    st4(Wb + ks * SCR_KS + (rbase + ri) * LDW + cg_ * 8,
        make_float4(acc[ri][0], acc[ri][1], acc[ri][2], acc[ri][3]));
    st4(Wb + ks * SCR_KS + (rbase + ri) * LDW + cg_ * 8 + 4,
        make_float4(acc[ri][4], acc[ri][5], acc[ri][6], acc[ri][7]));
  }
  __syncthreads();
  const int fr = tid >> 5, fc = (tid & 31) << 2;
  float4 s = make_float4(0.f, 0.f, 0.f, 0.f);
#pragma unroll
  for (int kk = 0; kk < 8; ++kk) {
    float4 v = ld4(Wb + kk * SCR_KS + fr * LDW + fc);
    s.x += v.x; s.y += v.y; s.z += v.z; s.w += v.w;
  }
  float* dp = dest + fr * LDW + fc;
  if (ADD) { float4 o = ld4(dp); s.x += o.x; s.y += o.y; s.z += o.z; s.w += o.w; }
  st4(dp, s);
  __syncthreads();
}
__device__ __forceinline__ void gru_out(float p0, float p1, float p2, float p3,
                                        float bi0, float bi1, float bi2,
                                        float bh0, float bh1, float bh2,
                                        float hv, float* o) {
  const float rg = sigm(p0 + bi0 + bh0);
  const float zg = sigm(p1 + bi1 + bh1);
  const float ng = tanhf(p2 + bi2 + rg * (p3 + bh2));
  *o = (1.f - zg) * ng + zg * hv;
}
__global__ __launch_bounds__(512) void k_main0(
    const float* __restrict__ enc, const float* __restrict__ fcn,
    const float* __restrict__ W0,
    const float* __restrict__ A1, const float* __restrict__ b1,
    const float* __restrict__ wih, const float* __restrict__ whh,
    const float* __restrict__ bih, const float* __restrict__ bhh,
    const float* __restrict__ outw, const float* __restrict__ outb,
    float* __restrict__ h, float* __restrict__ out) {
  __shared__ float Wb[16960];
  __shared__ float el[16 * LDW], hrep[16 * LDW], al[16 * LDW], hn[16 * LDW];
  __shared__ float pre[4][16 * LDW];
  __shared__ float fl[16 * 36];
  const int tid = threadIdx.x, b0 = blockIdx.x * 16;
  {
    const int r = tid >> 5, c4 = (tid & 31) << 2;
    st4(el + r * LDW + c4, ld4(enc + ((size_t)(b0 + r) * NT + 0) * DH + c4));
  }
  {
    const int r = tid >> 5, cc = tid & 31;
    fl[r * 36 + cc] = fcn[(size_t)(b0 + r) * DI + cc];
  }
  __syncthreads();
  {
    const int r = tid >> 5, fc = (tid & 31) << 2;
    st4(hrep + r * LDW + fc, ld4(fl + r * 36 + (fc & 31)));
  }
  stage128(Wb, W0, 32, 128, tid);
  __syncthreads();
  {
    const int r = tid >> 5, q = tid & 31;
    float acc = 0.f;
#pragma unroll 8
    for (int k4 = 0; k4 < 32; ++k4)
      acc += dot4(ld4(Wb + q * LDW + k4 * 4), ld4(el + r * LDW + k4 * 4));
    hn[r * LDW + q] = acc;
  }
  __syncthreads();
  for (int idx = tid; idx < 512; idx += 512) {
    const int r = idx >> 4, c4 = (idx & 15) << 2;
    st4(Wb + r * 68 + c4, ld4(A1 + r * 64 + c4));
  }
  __syncthreads();
  {
    const int r = tid >> 5, i = tid & 31;
    float acc = b1[i];
#pragma unroll
    for (int k4 = 0; k4 < 8; ++k4)
      acc += dot4(ld4(Wb + i * 68 + k4 * 4), ld4(hn + r * LDW + k4 * 4));
#pragma unroll
    for (int k4 = 0; k4 < 8; ++k4)
      acc += dot4(ld4(Wb + i * 68 + 32 + k4 * 4), ld4(fl + r * 36 + k4 * 4));
    al[r * LDW + i] = tanhf(acc);
  }
  __syncthreads();
  for (int idx = tid; idx < 384 * 8; idx += 512) {
    const int r = idx >> 3, c4 = (idx & 7) << 2;
    st4(Wb + r * 36 + c4, ld4(wih + r * 32 + c4));
  }
  __syncthreads();
  {
    const int r = tid >> 5, ccc = tid & 31;
#pragma unroll
    for (int m = 0; m < 12; ++m) {
      const int cc = ccc + 32 * m, g = cc >> 7, col = cc & 127;
      float acc = 0.f;
#pragma unroll
      for (int k4 = 0; k4 < 8; ++k4)
        acc += dot4(ld4(Wb + cc * 36 + k4 * 4), ld4(al + r * LDW + k4 * 4));
      pre[(g == 2) ? 2 : g][r * LDW + col] = acc;
    }
  }
  __syncthreads();
  stage128(Wb, whh, 128, 128, tid);          __syncthreads();
  phase128<1>(Wb, hrep, pre[0], tid);
  stage128(Wb, whh + 16384, 128, 128, tid);  __syncthreads();
  phase128<1>(Wb, hrep, pre[1], tid);
  stage128(Wb, whh + 32768, 128, 128, tid);  __syncthreads();
  phase128<0>(Wb, hrep, pre[3], tid);
  {
    const int fr = tid >> 5, fc = (tid & 31) << 2;
    float4 p0 = ld4(&pre[0][fr * LDW + fc]), p1 = ld4(&pre[1][fr * LDW + fc]);
    float4 p2 = ld4(&pre[2][fr * LDW + fc]), p3 = ld4(&pre[3][fr * LDW + fc]);
    float4 bi0 = ld4(bih + fc), bi1 = ld4(bih + DH + fc), bi2 = ld4(bih + 2 * DH + fc);
    float4 bh0 = ld4(bhh + fc), bh1 = ld4(bhh + DH + fc), bh2 = ld4(bhh + 2 * DH + fc);
    float4 hv = ld4(hrep + fr * LDW + fc);
    float o0, o1, o2, o3;
    gru_out(p0.x, p1.x, p2.x, p3.x, bi0.x, bi1.x, bi2.x, bh0.x, bh1.x, bh2.x, hv.x, &o0);
    gru_out(p0.y, p1.y, p2.y, p3.y, bi0.y, bi1.y, bi2.y, bh0.y, bh1.y, bh2.y, hv.y, &o1);
    gru_out(p0.z, p1.z, p2.z, p3.z, bi0.z, bi1.z, bi2.z, bh0.z, bh1.z, bh2.z, hv.z, &o2);
    gru_out(p0.w, p1.w, p2.w, p3.w, bi0.w, bi1.w, bi2.w, bh0.w, bh1.w, bh2.w, hv.w, &o3);
    float4 hnew = make_float4(o0, o1, o2, o3);
    st4(hn + fr * LDW + fc, hnew);
    st4(h + (size_t)(b0 + fr) * DH + fc, hnew);
  }
  __syncthreads();
  stage128(Wb, outw, 32, 128, tid);
  __syncthreads();
  {
    const int r = tid >> 5, cc = tid & 31;
    float acc = outb[cc];
#pragma unroll 8
    for (int k4 = 0; k4 < 32; ++k4)
      acc += dot4(ld4(Wb + cc * LDW + k4 * 4), ld4(hn + r * LDW + k4 * 4));
    out[((size_t)(b0 + r) * NT + 0) * DI + cc] = acc;
  }
}

extern "C" void kernel_launch(void* const* d_in, const int* in_sizes, int n_in,
                              void* d_out, int out_size, void* d_ws, size_t ws_size,
                              hipStream_t stream) {
  (void)in_sizes; (void)n_in; (void)out_size; (void)ws_size;
  const float* fcn  = (const float*)d_in[0];
  const float* enc  = (const float*)d_in[1];
  const float* a1w  = (const float*)d_in[2];
  const float* a1b  = (const float*)d_in[3];
  const float* a2w  = (const float*)d_in[4];
  const float* a2b  = (const float*)d_in[5];
  const float* w1ih = (const float*)d_in[6];
  const float* w1hh = (const float*)d_in[7];
  const float* b1ih = (const float*)d_in[8];
  const float* b1hh = (const float*)d_in[9];
  const float* w2ih = (const float*)d_in[10];
  const float* w2hh = (const float*)d_in[11];
  const float* b2ih = (const float*)d_in[12];
  const float* b2hh = (const float*)d_in[13];
  const float* outw = (const float*)d_in[14];
  const float* outb = (const float*)d_in[15];
  float* out = (float*)d_out;
  float* ws  = (float*)d_ws;

  float* h     = ws;                                       // 524288 f32
  float* spart = ws + 524288;                              // 64*128*128 f32 (4 MB, bootstrap)
  float* Wbuf  = ws + 1572864;                             // 16384 f32
  float* Sbuf  = ws + 1589248;                             // 4 x 16384 f32
  unsigned short* wbf = (unsigned short*)(ws + 1654784);   // 147456 bf16
  unsigned short* Wmb = (unsigned short*)(ws + 1728512);   // 16384 bf16

  k_prep<<<288, 512, 0, stream>>>(a2w, w2ih, w2hh, outw, wbf);

  // step 0 (fp32 path)
  k_scores<DI><<<64, 512, 0, stream>>>(fcn, enc, 0, spart);
  k_soft<DI, 64><<<DI, 128, 0, stream>>>(spart, Wbuf, Wmb);
  k_main0<<<BZ / 16, 512, 0, stream>>>(enc, fcn, Wbuf, a1w, a1b,
                                       w1ih, w1hh, b1ih, b1hh, outw, outb, h, out);
  // bootstrap raw scores for t=1 into Sbuf[1]; zero Sbuf[2]
  k_scores<DH><<<64, 512, 0, stream>>>(h, enc, 1, spart);
  k_sum<<<128, 128, 0, stream>>>(spart, Sbuf + 16384, Sbuf + 2 * 16384);

  // steps 1..127: one kernel per step
  for (int t = 1; t < NT; ++t) {
    const int do_next = (t < NT - 1) ? 1 : 0;
    const float* Srd = Sbuf + (size_t)(t & 3) * 16384;
    float* Sac = Sbuf + (size_t)((t + 1) & 3) * 16384;
    float* Szr = Sbuf + (size_t)((t + 2) & 3) * 16384;
    k_step3<<<128, 512, 0, stream>>>(enc, t, do_next, Srd, Sac, Szr, wbf, a2b,
                                     b2ih, b2hh, outb, h, out);
  }
}